// Round 6
// baseline (108.009 us; speedup 1.0000x reference)
//
#include <hip/hip_runtime.h>
#include <math.h>

// Problem constants (B=2, C=64, inter=32, H=W=80 -> N=6400)
#define BATCH 2
#define CH    64
#define INTER 32
#define NPOS  6400
#define NTILE 50          // N / 128 key tiles per batch
#define LOG2E 1.44269504088896f
#define SPLIT 10          // key-dim split factor
#define TPB   5           // 128-key tiles per split chunk (5*128*10 = 6400)

typedef _Float16 f16x8 __attribute__((ext_vector_type(8)));  // MFMA A/B frag
typedef _Float16 f16x2 __attribute__((ext_vector_type(2)));
typedef _Float16 h4    __attribute__((ext_vector_type(4)));
typedef float    f32x4 __attribute__((ext_vector_type(4)));  // MFMA C/D

// v_cvt_pkrtz returns __fp16x2; bit-identical to _Float16x2 -> bit_cast.
static __device__ __forceinline__ f16x2 pkrtz(float a, float b) {
    return __builtin_bit_cast(f16x2, __builtin_amdgcn_cvt_pkrtz(a, b));
}

// ---------------------------------------------------------------------------
// FRAGMENT-PACKED K/V layout (verified R2).  For each 128-key tile T the
// flash kernel consumes exactly 8 K-fragments and 8 V-fragments, each a
// 64-lane x 16B wave read, stored EXACTLY in consumption order in DRAM:
//   Kf unit ((b*50+T)*8 + g)*64 + lane,  lane = quad*16 + n16 holds
//     K[key=T*128+g*16+n16][dims quad*8..+7].
//   Vf unit ((b*50+T)*8 + kc*2+half)*64 + lane,  lane = qd*16 + d15 holds
//     V^T[dim=half*16+d15][slots kc*32+qd*8..+7],
//     slot(kk) = (g>>1)*32 + qd*8 + (g&1)*4 + rr  (verified R7/R10/R12 perm).
// ---------------------------------------------------------------------------

// ---------------------------------------------------------------------------
// Kernel 1: projections -> fp16 workspace (R2-verified 3-pass version).
// Grid (N/64, 3, B); blockIdx.y: 0: theta->Qh, 1: phi->Kf, 2: g->Vf.
// ---------------------------------------------------------------------------
__global__ __launch_bounds__(256) void nlb_proj_kernel(
    const float* __restrict__ x,
    const float* __restrict__ g_w,
    const float* __restrict__ th_w,
    const float* __restrict__ ph_w,
    _Float16* __restrict__ Qh, _Float16* __restrict__ Kf,
    _Float16* __restrict__ Vf)
{
    const int b  = blockIdx.z;
    const int p  = blockIdx.y;
    const int n0 = blockIdx.x * 64;
    const int t  = threadIdx.x;
    const int w  = __builtin_amdgcn_readfirstlane(t) >> 6;  // wave id (uniform)
    const int lane = t & 63;

    const float* wsrc = (p == 0) ? th_w : (p == 1) ? ph_w : g_w;
    const float* xg = x + (size_t)b * CH * NPOS + n0 + lane;

    float xr[64];
    #pragma unroll
    for (int c = 0; c < 64; c++) xr[c] = xg[(size_t)c * NPOS];

    __shared__ float buf[32][65];

    float accs[8];
    #pragma unroll
    for (int rr = 0; rr < 8; rr++) {
        const int row = w * 8 + rr;                  // wave-uniform
        const float* wr = wsrc + row * 64;           // -> scalar loads
        float a0 = 0.f, a1 = 0.f, a2 = 0.f, a3 = 0.f;
        #pragma unroll
        for (int c = 0; c < 16; c++) {
            a0 += wr[c]      * xr[c];
            a1 += wr[c + 16] * xr[c + 16];
            a2 += wr[c + 32] * xr[c + 32];
            a3 += wr[c + 48] * xr[c + 48];
        }
        accs[rr] = (a0 + a1) + (a2 + a3);
    }

    if (p == 2) {   // g -> Vf (fragment-packed, direct store)
        const int n  = n0 + lane;
        const int T  = n >> 7, kk = n & 127;
        const int g  = kk >> 4, qd = (kk >> 2) & 3, r3 = kk & 3;
        const int kc = g >> 1, j = (g & 1) * 4 + r3;
        const int half = w >> 1, d15base = (w & 1) * 8;
        _Float16* vb = Vf +
            (((((size_t)b * NTILE + T) * 8 + kc * 2 + half) * 64
              + qd * 16 + d15base) * 8 + j);
        #pragma unroll
        for (int rr = 0; rr < 8; rr++)
            vb[(size_t)rr * 8] = (_Float16)accs[rr];   // d15 += 1 -> +8 elems
        return;
    }

    #pragma unroll
    for (int rr = 0; rr < 8; rr++) buf[w * 8 + rr][lane] = accs[rr];
    __syncthreads();

    const int pos = t >> 2, ic = t & 3;   // 8 consecutive inter-ch per thread
    if (p == 0) {   // theta -> Qh (linear, scaled by log2(e))
        f16x8 hv;
        #pragma unroll
        for (int j = 0; j < 8; j++)
            hv[j] = (_Float16)(buf[ic * 8 + j][pos] * LOG2E);
        *(f16x8*)(Qh + ((size_t)b * NPOS + n0 + pos) * 32 + ic * 8) = hv;
    } else {        // phi -> Kf (fragment-packed)
        f16x8 hv;
        #pragma unroll
        for (int j = 0; j < 8; j++)
            hv[j] = (_Float16)buf[ic * 8 + j][pos];
        const int key = n0 + pos, T = key >> 7, kk = key & 127;
        const int g = kk >> 4, m16 = kk & 15;
        ((f16x8*)Kf)[(((size_t)b * NTILE + T) * 8 + g) * 64 + ic * 16 + m16] = hv;
    }
}

// ---------------------------------------------------------------------------
// Kernel 2: fp16 MFMA flash attention, split-K, register-P dataflow.
// R6: 32 queries/wave (K/V fragment reads shared by 2 MFMAs -> LDS issue
// halved per query) AND 512-thread blocks (8 waves) -> 2 blocks/CU = 16
// waves/CU (the R5 regression was dropping to 8), AND grid = 500 blocks ->
// ONE residency round (R2 needed two).  To hold the 128-VGPR ceiling that
// 16 waves/CU requires, score liveness is minimized: each group's P is
// packed to fp16 right after its softmax (sc dies at pack; peak ~64 f32
// scores), no V-register hoisting (the R4 spill trap).
// __launch_bounds__(512,4) pins the allocator to 4 waves/EU (<=128 VGPR).
// One barrier; whole 640-key chunk staged once (80KB fragment-packed).
// Grid (N/256, SPLIT, B) = 500 blocks.
//   S^T = K Q^T : A = K frag (LDS), B = Q frag (regs) x2 groups.
//     C-layout: lane(n16,quad) holds S^T[key=g*16+quad*4+r][q=n16].
//   softmax: per-group lane-local max tree + shfl_xor(16,32); l deferred.
//   O^T = V^T P^T : A = V frag (LDS, slot-permuted), B = pb packed x2.
// ---------------------------------------------------------------------------
__global__ __launch_bounds__(512, 4) void nlb_flash_kernel(
    const _Float16* __restrict__ Qh, const _Float16* __restrict__ Kf,
    const _Float16* __restrict__ Vf,
    _Float16* __restrict__ Opart, float2* __restrict__ ml)
{
    __shared__ f16x8 smem[5120];   // 80KB: [0,2560) = K units, [2560,5120) = V

    const int b     = blockIdx.z;
    const int split = blockIdx.y;
    const int t     = threadIdx.x;          // 0..511
    const int w     = t >> 6;               // 0..7
    const int lane  = t & 63;
    const int n16   = lane & 15;
    const int quad  = lane >> 4;
    const int q0    = blockIdx.x * 256 + w * 32;

    // Two Q fragments: queries q0+n16 (group 0) and q0+16+n16 (group 1)
    const f16x8 qa0 = *(const f16x8*)(Qh + ((size_t)b * NPOS + q0 + n16) * 32 + quad * 8);
    const f16x8 qa1 = *(const f16x8*)(Qh + ((size_t)b * NPOS + q0 + 16 + n16) * 32 + quad * 8);

    // bulk stage: 2 contiguous 40KB fragment-packed copies (16B/thread x 5)
    {
        const f16x8* Ks = (const f16x8*)Kf + ((size_t)b * NTILE + split * TPB) * 512;
        const f16x8* Vs = (const f16x8*)Vf + ((size_t)b * NTILE + split * TPB) * 512;
        f16x8 st[5];
        #pragma unroll
        for (int c = 0; c < 5; c++) st[c] = Ks[c * 512 + t];
        #pragma unroll
        for (int c = 0; c < 5; c++) smem[c * 512 + t] = st[c];
        #pragma unroll
        for (int c = 0; c < 5; c++) st[c] = Vs[c * 512 + t];
        #pragma unroll
        for (int c = 0; c < 5; c++) smem[2560 + c * 512 + t] = st[c];
    }
    __syncthreads();   // the ONLY barrier in this kernel

    f32x4 o00 = (f32x4)0.f, o01 = (f32x4)0.f;   // group 0: dims 0-15 / 16-31
    f32x4 o10 = (f32x4)0.f, o11 = (f32x4)0.f;   // group 1
    float runm0 = -1e30f, lsum0 = 0.f;
    float runm1 = -1e30f, lsum1 = 0.f;

    for (int i = 0; i < TPB; i++) {
        const int kb = i * 512;          // K units of tile i
        const int vb = 2560 + i * 512;   // V units of tile i

        // S^T = K Q^T : each K fragment feeds BOTH query groups
        f32x4 sc0[8], sc1[8];
        #pragma unroll
        for (int g = 0; g < 8; g++) {
            f16x8 kf = smem[kb + g * 64 + lane];
            f32x4 z = (f32x4)0.f;
            sc0[g] = __builtin_amdgcn_mfma_f32_16x16x32_f16(kf, qa0, z, 0, 0, 0);
            sc1[g] = __builtin_amdgcn_mfma_f32_16x16x32_f16(kf, qa1, z, 0, 0, 0);
        }

        f16x8 pb0[4], pb1[4];   // packed P, group 0/1 (sc dies at pack)

        // softmax group 0 -> pack pb0
        {
            float mg[8];
            #pragma unroll
            for (int g = 0; g < 8; g++)
                mg[g] = fmaxf(fmaxf(sc0[g][0], sc0[g][1]), fmaxf(sc0[g][2], sc0[g][3]));
            float m = fmaxf(fmaxf(fmaxf(mg[0], mg[1]), fmaxf(mg[2], mg[3])),
                            fmaxf(fmaxf(mg[4], mg[5]), fmaxf(mg[6], mg[7])));
            m = fmaxf(m, __shfl_xor(m, 16));
            m = fmaxf(m, __shfl_xor(m, 32));
            float nm = fmaxf(runm0, m);
            float a  = __builtin_amdgcn_exp2f(runm0 - nm);
            runm0 = nm;
            float ls = 0.f;
            #pragma unroll
            for (int g = 0; g < 8; g++) {
                #pragma unroll
                for (int r = 0; r < 4; r++) {
                    float p = __builtin_amdgcn_exp2f(sc0[g][r] - nm);
                    sc0[g][r] = p;
                    ls += p;
                }
            }
            lsum0 = lsum0 * a + ls;
            o00 *= a;
            o01 *= a;
            #pragma unroll
            for (int kc = 0; kc < 4; kc++) {
                union { f16x8 v; f16x2 h2[4]; } pb;
                pb.h2[0] = pkrtz(sc0[kc * 2][0],     sc0[kc * 2][1]);
                pb.h2[1] = pkrtz(sc0[kc * 2][2],     sc0[kc * 2][3]);
                pb.h2[2] = pkrtz(sc0[kc * 2 + 1][0], sc0[kc * 2 + 1][1]);
                pb.h2[3] = pkrtz(sc0[kc * 2 + 1][2], sc0[kc * 2 + 1][3]);
                pb0[kc] = pb.v;
            }
        }
        // softmax group 1 -> pack pb1
        {
            float mg[8];
            #pragma unroll
            for (int g = 0; g < 8; g++)
                mg[g] = fmaxf(fmaxf(sc1[g][0], sc1[g][1]), fmaxf(sc1[g][2], sc1[g][3]));
            float m = fmaxf(fmaxf(fmaxf(mg[0], mg[1]), fmaxf(mg[2], mg[3])),
                            fmaxf(fmaxf(mg[4], mg[5]), fmaxf(mg[6], mg[7])));
            m = fmaxf(m, __shfl_xor(m, 16));
            m = fmaxf(m, __shfl_xor(m, 32));
            float nm = fmaxf(runm1, m);
            float a  = __builtin_amdgcn_exp2f(runm1 - nm);
            runm1 = nm;
            float ls = 0.f;
            #pragma unroll
            for (int g = 0; g < 8; g++) {
                #pragma unroll
                for (int r = 0; r < 4; r++) {
                    float p = __builtin_amdgcn_exp2f(sc1[g][r] - nm);
                    sc1[g][r] = p;
                    ls += p;
                }
            }
            lsum1 = lsum1 * a + ls;
            o10 *= a;
            o11 *= a;
            #pragma unroll
            for (int kc = 0; kc < 4; kc++) {
                union { f16x8 v; f16x2 h2[4]; } pb;
                pb.h2[0] = pkrtz(sc1[kc * 2][0],     sc1[kc * 2][1]);
                pb.h2[1] = pkrtz(sc1[kc * 2][2],     sc1[kc * 2][3]);
                pb.h2[2] = pkrtz(sc1[kc * 2 + 1][0], sc1[kc * 2 + 1][1]);
                pb.h2[3] = pkrtz(sc1[kc * 2 + 1][2], sc1[kc * 2 + 1][3]);
                pb1[kc] = pb.v;
            }
        }

        // O^T += V^T P^T : each V fragment feeds BOTH query groups
        #pragma unroll
        for (int kc = 0; kc < 4; kc++) {
            f16x8 v0 = smem[vb + (kc * 2) * 64 + lane];       // dims 0..15
            f16x8 v1 = smem[vb + (kc * 2 + 1) * 64 + lane];   // dims 16..31
            o00 = __builtin_amdgcn_mfma_f32_16x16x32_f16(v0, pb0[kc], o00, 0, 0, 0);
            o01 = __builtin_amdgcn_mfma_f32_16x16x32_f16(v1, pb0[kc], o01, 0, 0, 0);
            o10 = __builtin_amdgcn_mfma_f32_16x16x32_f16(v0, pb1[kc], o10, 0, 0, 0);
            o11 = __builtin_amdgcn_mfma_f32_16x16x32_f16(v1, pb1[kc], o11, 0, 0, 0);
        }
    }

    // epilogue: finish l across quads, normalize, store O^T + (m,l), both groups
    lsum0 += __shfl_xor(lsum0, 16);
    lsum0 += __shfl_xor(lsum0, 32);
    lsum1 += __shfl_xor(lsum1, 16);
    lsum1 += __shfl_xor(lsum1, 32);
    const float inv0 = 1.f / lsum0, inv1 = 1.f / lsum1;
    const size_t base0 = ((size_t)(b * SPLIT + split) * NPOS + q0 + n16) * 32;
    const size_t base1 = base0 + (size_t)16 * 32;
    h4 h00, h01, h10, h11;
    #pragma unroll
    for (int r = 0; r < 4; r++) {
        h00[r] = (_Float16)(o00[r] * inv0);
        h01[r] = (_Float16)(o01[r] * inv0);
        h10[r] = (_Float16)(o10[r] * inv1);
        h11[r] = (_Float16)(o11[r] * inv1);
    }
    *(h4*)(Opart + base0 + quad * 4)      = h00;
    *(h4*)(Opart + base0 + 16 + quad * 4) = h01;
    *(h4*)(Opart + base1 + quad * 4)      = h10;
    *(h4*)(Opart + base1 + 16 + quad * 4) = h11;
    if (quad == 0) {
        ml[(size_t)(b * SPLIT + split) * NPOS + q0 + n16]      = make_float2(runm0, lsum0);
        ml[(size_t)(b * SPLIT + split) * NPOS + q0 + 16 + n16] = make_float2(runm1, lsum1);
    }
}

// ---------------------------------------------------------------------------
// Kernel 3: flash-combine the SPLIT partials + W-projection + residual.
// Grid (N/32, B). Opart layout [b][split][q][32] -> coalesced 8B reads.
// ---------------------------------------------------------------------------
__global__ __launch_bounds__(256) void nlb_combine_kernel(
    const _Float16* __restrict__ Opart, const float2* __restrict__ ml,
    const float* __restrict__ w_w, const float* __restrict__ x,
    float* __restrict__ out)
{
    __shared__ float wf[64][33];
    __shared__ float wts[32][12];
    __shared__ float of[32][33];

    const int b  = blockIdx.y;
    const int q0 = blockIdx.x * 32;
    const int t  = threadIdx.x;

    for (int idx = t; idx < 2048; idx += 256) wf[idx >> 5][idx & 31] = w_w[idx];

    if (t < 32) {   // merge coefficients c_s = exp2(m_s-m*)*l_s / sum
        float2 v[SPLIT];
        float m = -1e30f;
        #pragma unroll
        for (int s = 0; s < SPLIT; s++) {
            v[s] = ml[(size_t)(b * SPLIT + s) * NPOS + q0 + t];
            m = fmaxf(m, v[s].x);
        }
        float suml = 0.f;
        #pragma unroll
        for (int s = 0; s < SPLIT; s++) {
            float wgt = __builtin_amdgcn_exp2f(v[s].x - m) * v[s].y;
            wts[t][s] = wgt;
            suml += wgt;
        }
        float inv = 1.f / suml;
        #pragma unroll
        for (int s = 0; s < SPLIT; s++) wts[t][s] *= inv;
    }
    __syncthreads();

    {   // merge partial O: thread -> (q = t>>3, dims dg*4..dg*4+3) COALESCED
        const int q = t >> 3, dg = t & 7;
        float a0 = 0.f, a1 = 0.f, a2 = 0.f, a3 = 0.f;
        #pragma unroll
        for (int s = 0; s < SPLIT; s++) {
            h4 hv = *(const h4*)(Opart +
                ((size_t)(b * SPLIT + s) * NPOS + q0 + q) * 32 + dg * 4);
            float c = wts[q][s];
            a0 += c * (float)hv[0]; a1 += c * (float)hv[1];
            a2 += c * (float)hv[2]; a3 += c * (float)hv[3];
        }
        of[q][dg * 4]     = a0; of[q][dg * 4 + 1] = a1;
        of[q][dg * 4 + 2] = a2; of[q][dg * 4 + 3] = a3;
    }
    __syncthreads();

    {   // y = W o + x: thread -> (query, 8 channels)
        const int q = t & 31, cg = t >> 5;
        const float* xb = x   + (size_t)b * CH * NPOS + q0 + q;
        float*       ob = out + (size_t)b * CH * NPOS + q0 + q;
        #pragma unroll
        for (int cc = 0; cc < 8; cc++) {
            int ch = cg * 8 + cc;
            float acc = 0.f;
            #pragma unroll
            for (int i = 0; i < 32; i++) acc += wf[ch][i] * of[q][i];
            ob[(size_t)ch * NPOS] = acc + xb[(size_t)ch * NPOS];
        }
    }
}

extern "C" void kernel_launch(void* const* d_in, const int* in_sizes, int n_in,
                              void* d_out, int out_size, void* d_ws, size_t ws_size,
                              hipStream_t stream) {
    const float* x    = (const float*)d_in[0];
    const float* g_w  = (const float*)d_in[1];
    const float* th_w = (const float*)d_in[2];
    const float* ph_w = (const float*)d_in[3];
    const float* w_w  = (const float*)d_in[4];
    float* out = (float*)d_out;

    const size_t SZ = (size_t)BATCH * NPOS * INTER;   // 409600 elements
    _Float16* Qh = (_Float16*)d_ws;
    _Float16* Kf = Qh + SZ;
    _Float16* Vf = Kf + SZ;
    _Float16* Opart = Vf + SZ;                         // [B][SPLIT][N][32]
    float2*   ml    = (float2*)(Opart + SZ * SPLIT);   // [B][SPLIT][N]

    nlb_proj_kernel<<<dim3(NPOS / 64, 3, BATCH), 256, 0, stream>>>(
        x, g_w, th_w, ph_w, Qh, Kf, Vf);
    nlb_flash_kernel<<<dim3(NPOS / 256, SPLIT, BATCH), 512, 0, stream>>>(
        Qh, Kf, Vf, Opart, ml);
    nlb_combine_kernel<<<dim3(NPOS / 32, BATCH), 256, 0, stream>>>(
        Opart, ml, w_w, x, out);
}

// Round 7
// 103.902 us; speedup vs baseline: 1.0395x; 1.0395x over previous
//
#include <hip/hip_runtime.h>
#include <math.h>

// Problem constants (B=2, C=64, inter=32, H=W=80 -> N=6400)
#define BATCH 2
#define CH    64
#define INTER 32
#define NPOS  6400
#define NTILE 50          // N / 128 key tiles per batch
#define LOG2E 1.44269504088896f
#define SPLIT 10          // key-dim split factor
#define TPB   5           // 128-key tiles per split chunk (5*128*10 = 6400)

typedef _Float16 f16x8 __attribute__((ext_vector_type(8)));  // MFMA A/B frag
typedef _Float16 f16x2 __attribute__((ext_vector_type(2)));
typedef _Float16 h4    __attribute__((ext_vector_type(4)));
typedef float    f32x4 __attribute__((ext_vector_type(4)));  // MFMA C/D

// v_cvt_pkrtz returns __fp16x2; bit-identical to _Float16x2 -> bit_cast.
static __device__ __forceinline__ f16x2 pkrtz(float a, float b) {
    return __builtin_bit_cast(f16x2, __builtin_amdgcn_cvt_pkrtz(a, b));
}

// ---------------------------------------------------------------------------
// FRAGMENT-PACKED K/V layout (verified R2).  For each 128-key tile T the
// flash kernel consumes exactly 8 K-fragments and 8 V-fragments, each a
// 64-lane x 16B wave read, stored EXACTLY in consumption order in DRAM:
//   Kf unit ((b*50+T)*8 + g)*64 + lane,  lane = quad*16 + n16 holds
//     K[key=T*128+g*16+n16][dims quad*8..+7].
//   Vf unit ((b*50+T)*8 + kc*2+half)*64 + lane,  lane = qd*16 + d15 holds
//     V^T[dim=half*16+d15][slots kc*32+qd*8..+7],
//     slot(kk) = (g>>1)*32 + qd*8 + (g&1)*4 + rr  (verified R7/R10/R12 perm).
// ---------------------------------------------------------------------------

// ---------------------------------------------------------------------------
// Kernel 1: projections -> fp16 workspace (R2-verified 3-pass version).
// Grid (N/64, 3, B); blockIdx.y: 0: theta->Qh, 1: phi->Kf, 2: g->Vf.
// ---------------------------------------------------------------------------
__global__ __launch_bounds__(256) void nlb_proj_kernel(
    const float* __restrict__ x,
    const float* __restrict__ g_w,
    const float* __restrict__ th_w,
    const float* __restrict__ ph_w,
    _Float16* __restrict__ Qh, _Float16* __restrict__ Kf,
    _Float16* __restrict__ Vf)
{
    const int b  = blockIdx.z;
    const int p  = blockIdx.y;
    const int n0 = blockIdx.x * 64;
    const int t  = threadIdx.x;
    const int w  = __builtin_amdgcn_readfirstlane(t) >> 6;  // wave id (uniform)
    const int lane = t & 63;

    const float* wsrc = (p == 0) ? th_w : (p == 1) ? ph_w : g_w;
    const float* xg = x + (size_t)b * CH * NPOS + n0 + lane;

    float xr[64];
    #pragma unroll
    for (int c = 0; c < 64; c++) xr[c] = xg[(size_t)c * NPOS];

    __shared__ float buf[32][65];

    float accs[8];
    #pragma unroll
    for (int rr = 0; rr < 8; rr++) {
        const int row = w * 8 + rr;                  // wave-uniform
        const float* wr = wsrc + row * 64;           // -> scalar loads
        float a0 = 0.f, a1 = 0.f, a2 = 0.f, a3 = 0.f;
        #pragma unroll
        for (int c = 0; c < 16; c++) {
            a0 += wr[c]      * xr[c];
            a1 += wr[c + 16] * xr[c + 16];
            a2 += wr[c + 32] * xr[c + 32];
            a3 += wr[c + 48] * xr[c + 48];
        }
        accs[rr] = (a0 + a1) + (a2 + a3);
    }

    if (p == 2) {   // g -> Vf (fragment-packed, direct store)
        const int n  = n0 + lane;
        const int T  = n >> 7, kk = n & 127;
        const int g  = kk >> 4, qd = (kk >> 2) & 3, r3 = kk & 3;
        const int kc = g >> 1, j = (g & 1) * 4 + r3;
        const int half = w >> 1, d15base = (w & 1) * 8;
        _Float16* vb = Vf +
            (((((size_t)b * NTILE + T) * 8 + kc * 2 + half) * 64
              + qd * 16 + d15base) * 8 + j);
        #pragma unroll
        for (int rr = 0; rr < 8; rr++)
            vb[(size_t)rr * 8] = (_Float16)accs[rr];   // d15 += 1 -> +8 elems
        return;
    }

    #pragma unroll
    for (int rr = 0; rr < 8; rr++) buf[w * 8 + rr][lane] = accs[rr];
    __syncthreads();

    const int pos = t >> 2, ic = t & 3;   // 8 consecutive inter-ch per thread
    if (p == 0) {   // theta -> Qh (linear, scaled by log2(e))
        f16x8 hv;
        #pragma unroll
        for (int j = 0; j < 8; j++)
            hv[j] = (_Float16)(buf[ic * 8 + j][pos] * LOG2E);
        *(f16x8*)(Qh + ((size_t)b * NPOS + n0 + pos) * 32 + ic * 8) = hv;
    } else {        // phi -> Kf (fragment-packed)
        f16x8 hv;
        #pragma unroll
        for (int j = 0; j < 8; j++)
            hv[j] = (_Float16)buf[ic * 8 + j][pos];
        const int key = n0 + pos, T = key >> 7, kk = key & 127;
        const int g = kk >> 4, m16 = kk & 15;
        ((f16x8*)Kf)[(((size_t)b * NTILE + T) * 8 + g) * 64 + ic * 16 + m16] = hv;
    }
}

// ---------------------------------------------------------------------------
// Kernel 2: fp16 MFMA flash attention, split-K, register-P dataflow.
// R7 = R2's verified structure (16 q/wave, 512 thr, 8 waves, one barrier,
// 80KB bulk-staged LDS, 2 blocks/CU) + 1-DEEP CROSS-TILE SCORE PIPELINE:
// tile i+1's eight S-MFMAs (independent of tile i's softmax) are issued
// BEFORE tile i's serial softmax chain, so the MFMA pipe and the K ds_reads
// of the next tile shadow the fmax/exp dependency chain.  This spends the
// free VGPR headroom (R2 sat at 64; LDS caps occupancy at 4 waves/SIMD for
// anything <=128 VGPR, so up to 128 is occupancy-free).  Full unroll over
// TPB keeps sc[2][8] statically indexed (no scratch).  launch_bounds(512,4)
// pins <=128 VGPR; loop peak ~105 leaves headroom (the R6 spill trap sat
// at ~127).
// Grid (N/128, SPLIT, B) = 1000 blocks.
//   S^T = K Q^T : A = K frag (LDS), B = Q frag (regs).
//     C-layout: lane(n16,quad) holds S^T[key=g*16+quad*4+r][q=n16].
//   softmax: lane-local fmax tree + shfl_xor(16,32); l cross-quad deferred.
//   O^T = V^T P^T : A = V frag (LDS, slot-permuted), B = pb packed.
// ---------------------------------------------------------------------------
__global__ __launch_bounds__(512, 4) void nlb_flash_kernel(
    const _Float16* __restrict__ Qh, const _Float16* __restrict__ Kf,
    const _Float16* __restrict__ Vf,
    _Float16* __restrict__ Opart, float2* __restrict__ ml)
{
    __shared__ f16x8 smem[5120];   // 80KB: [0,2560) = K units, [2560,5120) = V

    const int b     = blockIdx.z;
    const int split = blockIdx.y;
    const int t     = threadIdx.x;
    const int w     = t >> 6;
    const int lane  = t & 63;
    const int n16   = lane & 15;
    const int quad  = lane >> 4;
    const int q0    = blockIdx.x * 128 + w * 16;

    // Q fragment (B-operand of Q^T) — issued before staging, lands under it
    const f16x8 qa = *(const f16x8*)(Qh + ((size_t)b * NPOS + q0 + n16) * 32 + quad * 8);

    // bulk stage: 2 contiguous 40KB fragment-packed copies (16B/thread x 5)
    {
        const f16x8* Ks = (const f16x8*)Kf + ((size_t)b * NTILE + split * TPB) * 512;
        const f16x8* Vs = (const f16x8*)Vf + ((size_t)b * NTILE + split * TPB) * 512;
        f16x8 st[5];
        #pragma unroll
        for (int c = 0; c < 5; c++) st[c] = Ks[c * 512 + t];
        #pragma unroll
        for (int c = 0; c < 5; c++) smem[c * 512 + t] = st[c];
        #pragma unroll
        for (int c = 0; c < 5; c++) st[c] = Vs[c * 512 + t];
        #pragma unroll
        for (int c = 0; c < 5; c++) smem[2560 + c * 512 + t] = st[c];
    }
    __syncthreads();   // the ONLY barrier in this kernel

    f32x4 o0 = (f32x4)0.f;              // dims quad*4+r      (query n16)
    f32x4 o1 = (f32x4)0.f;              // dims 16+quad*4+r
    float runm = -1e30f, lsum = 0.f;    // per-lane state for query n16

    f32x4 sc[2][8];                     // double-buffered score tiles

    // prologue: S of tile 0
    #pragma unroll
    for (int g = 0; g < 8; g++) {
        f16x8 kf = smem[g * 64 + lane];
        f32x4 z = (f32x4)0.f;
        sc[0][g] = __builtin_amdgcn_mfma_f32_16x16x32_f16(kf, qa, z, 0, 0, 0);
    }

    #pragma unroll
    for (int i = 0; i < TPB; i++) {
        const int cur = i & 1;          // compile-time after full unroll
        const int nxt = cur ^ 1;
        const int vb  = 2560 + i * 512; // V units of tile i

        // S of tile i+1 issued FIRST: its ds_reads + MFMAs overlap the
        // serial softmax chain of tile i (results consumed next iter).
        if (i + 1 < TPB) {
            const int kbn = (i + 1) * 512;
            #pragma unroll
            for (int g = 0; g < 8; g++) {
                f16x8 kf = smem[kbn + g * 64 + lane];
                f32x4 z = (f32x4)0.f;
                sc[nxt][g] = __builtin_amdgcn_mfma_f32_16x16x32_f16(kf, qa, z, 0, 0, 0);
            }
        }

        // softmax over this query's 128 keys (lane owns 32; rest in n16+16k)
        float mg[8];
        #pragma unroll
        for (int g = 0; g < 8; g++)
            mg[g] = fmaxf(fmaxf(sc[cur][g][0], sc[cur][g][1]),
                          fmaxf(sc[cur][g][2], sc[cur][g][3]));
        float m = fmaxf(fmaxf(fmaxf(mg[0], mg[1]), fmaxf(mg[2], mg[3])),
                        fmaxf(fmaxf(mg[4], mg[5]), fmaxf(mg[6], mg[7])));
        m = fmaxf(m, __shfl_xor(m, 16));
        m = fmaxf(m, __shfl_xor(m, 32));
        float nm = fmaxf(runm, m);
        float a  = __builtin_amdgcn_exp2f(runm - nm);
        runm = nm;
        float ls = 0.f;
        #pragma unroll
        for (int g = 0; g < 8; g++) {
            #pragma unroll
            for (int r = 0; r < 4; r++) {
                float p = __builtin_amdgcn_exp2f(sc[cur][g][r] - nm);
                sc[cur][g][r] = p;
                ls += p;
            }
        }
        lsum = lsum * a + ls;   // cross-quad sum deferred to epilogue
        o0 *= a;
        o1 *= a;

        // O^T += V^T P^T : pb[j] = P[key (kc*2+(j>>2))*16+quad*4+(j&3)]
        #pragma unroll
        for (int kc = 0; kc < 4; kc++) {
            union { f16x8 v; f16x2 h2[4]; } pb;
            pb.h2[0] = pkrtz(sc[cur][kc * 2][0],     sc[cur][kc * 2][1]);
            pb.h2[1] = pkrtz(sc[cur][kc * 2][2],     sc[cur][kc * 2][3]);
            pb.h2[2] = pkrtz(sc[cur][kc * 2 + 1][0], sc[cur][kc * 2 + 1][1]);
            pb.h2[3] = pkrtz(sc[cur][kc * 2 + 1][2], sc[cur][kc * 2 + 1][3]);
            f16x8 v0 = smem[vb + (kc * 2) * 64 + lane];       // dims 0..15
            f16x8 v1 = smem[vb + (kc * 2 + 1) * 64 + lane];   // dims 16..31
            o0 = __builtin_amdgcn_mfma_f32_16x16x32_f16(v0, pb.v, o0, 0, 0, 0);
            o1 = __builtin_amdgcn_mfma_f32_16x16x32_f16(v1, pb.v, o1, 0, 0, 0);
        }
    }

    // epilogue: finish l across quads, normalize, store O^T + (m,l)
    lsum += __shfl_xor(lsum, 16);
    lsum += __shfl_xor(lsum, 32);
    float invl = 1.f / lsum;
    const size_t base = ((size_t)(b * SPLIT + split) * NPOS + q0 + n16) * 32;
    h4 h0, h1;
    #pragma unroll
    for (int r = 0; r < 4; r++) {
        h0[r] = (_Float16)(o0[r] * invl);
        h1[r] = (_Float16)(o1[r] * invl);
    }
    *(h4*)(Opart + base + quad * 4)      = h0;
    *(h4*)(Opart + base + 16 + quad * 4) = h1;
    if (quad == 0)
        ml[(size_t)(b * SPLIT + split) * NPOS + q0 + n16] = make_float2(runm, lsum);
}

// ---------------------------------------------------------------------------
// Kernel 3: flash-combine the SPLIT partials + W-projection + residual.
// Grid (N/32, B). Opart layout [b][split][q][32] -> coalesced 8B reads.
// ---------------------------------------------------------------------------
__global__ __launch_bounds__(256) void nlb_combine_kernel(
    const _Float16* __restrict__ Opart, const float2* __restrict__ ml,
    const float* __restrict__ w_w, const float* __restrict__ x,
    float* __restrict__ out)
{
    __shared__ float wf[64][33];
    __shared__ float wts[32][12];
    __shared__ float of[32][33];

    const int b  = blockIdx.y;
    const int q0 = blockIdx.x * 32;
    const int t  = threadIdx.x;

    for (int idx = t; idx < 2048; idx += 256) wf[idx >> 5][idx & 31] = w_w[idx];

    if (t < 32) {   // merge coefficients c_s = exp2(m_s-m*)*l_s / sum
        float2 v[SPLIT];
        float m = -1e30f;
        #pragma unroll
        for (int s = 0; s < SPLIT; s++) {
            v[s] = ml[(size_t)(b * SPLIT + s) * NPOS + q0 + t];
            m = fmaxf(m, v[s].x);
        }
        float suml = 0.f;
        #pragma unroll
        for (int s = 0; s < SPLIT; s++) {
            float wgt = __builtin_amdgcn_exp2f(v[s].x - m) * v[s].y;
            wts[t][s] = wgt;
            suml += wgt;
        }
        float inv = 1.f / suml;
        #pragma unroll
        for (int s = 0; s < SPLIT; s++) wts[t][s] *= inv;
    }
    __syncthreads();

    {   // merge partial O: thread -> (q = t>>3, dims dg*4..dg*4+3) COALESCED
        const int q = t >> 3, dg = t & 7;
        float a0 = 0.f, a1 = 0.f, a2 = 0.f, a3 = 0.f;
        #pragma unroll
        for (int s = 0; s < SPLIT; s++) {
            h4 hv = *(const h4*)(Opart +
                ((size_t)(b * SPLIT + s) * NPOS + q0 + q) * 32 + dg * 4);
            float c = wts[q][s];
            a0 += c * (float)hv[0]; a1 += c * (float)hv[1];
            a2 += c * (float)hv[2]; a3 += c * (float)hv[3];
        }
        of[q][dg * 4]     = a0; of[q][dg * 4 + 1] = a1;
        of[q][dg * 4 + 2] = a2; of[q][dg * 4 + 3] = a3;
    }
    __syncthreads();

    {   // y = W o + x: thread -> (query, 8 channels)
        const int q = t & 31, cg = t >> 5;
        const float* xb = x   + (size_t)b * CH * NPOS + q0 + q;
        float*       ob = out + (size_t)b * CH * NPOS + q0 + q;
        #pragma unroll
        for (int cc = 0; cc < 8; cc++) {
            int ch = cg * 8 + cc;
            float acc = 0.f;
            #pragma unroll
            for (int i = 0; i < 32; i++) acc += wf[ch][i] * of[q][i];
            ob[(size_t)ch * NPOS] = acc + xb[(size_t)ch * NPOS];
        }
    }
}

extern "C" void kernel_launch(void* const* d_in, const int* in_sizes, int n_in,
                              void* d_out, int out_size, void* d_ws, size_t ws_size,
                              hipStream_t stream) {
    const float* x    = (const float*)d_in[0];
    const float* g_w  = (const float*)d_in[1];
    const float* th_w = (const float*)d_in[2];
    const float* ph_w = (const float*)d_in[3];
    const float* w_w  = (const float*)d_in[4];
    float* out = (float*)d_out;

    const size_t SZ = (size_t)BATCH * NPOS * INTER;   // 409600 elements
    _Float16* Qh = (_Float16*)d_ws;
    _Float16* Kf = Qh + SZ;
    _Float16* Vf = Kf + SZ;
    _Float16* Opart = Vf + SZ;                         // [B][SPLIT][N][32]
    float2*   ml    = (float2*)(Opart + SZ * SPLIT);   // [B][SPLIT][N]

    nlb_proj_kernel<<<dim3(NPOS / 64, 3, BATCH), 256, 0, stream>>>(
        x, g_w, th_w, ph_w, Qh, Kf, Vf);
    nlb_flash_kernel<<<dim3(NPOS / 128, SPLIT, BATCH), 512, 0, stream>>>(
        Qh, Kf, Vf, Opart, ml);
    nlb_combine_kernel<<<dim3(NPOS / 32, BATCH), 256, 0, stream>>>(
        Opart, ml, w_w, x, out);
}